// Round 1
// baseline (175.852 us; speedup 1.0000x reference)
//
#include <hip/hip_runtime.h>
#include <math.h>

#define NCLS 30
#define BATCH 16
#define NBOX 64
#define NB (BATCH * NBOX)   // 1024 boxes total

// ws layout (floats), per scale s stride 8:
//   ws[s*8+0] = sum softplus(obj)  over all cells
//   ws[s*8+1] = sum ce             over positive cells
//   ws[s*8+2] = sum smoothL1       over positive cells
//   ws[s*8+3] = npos (count of unique positive cells)
//   ws[s*8+4] = sum obj logits     over positive cells

__device__ __forceinline__ float softplusf(float x) {
    // log1p(exp(x)) — stable: for large x, result == x
    return (x > 20.0f) ? x : log1pf(expf(x));
}

__global__ __launch_bounds__(256) void detloss_main(
    const float* __restrict__ cls0, const float* __restrict__ reg0, const float* __restrict__ obj0,
    const float* __restrict__ cls1, const float* __restrict__ reg1, const float* __restrict__ obj1,
    const float* __restrict__ cls2, const float* __restrict__ reg2, const float* __restrict__ obj2,
    const float* __restrict__ boxes, const int* __restrict__ labels,
    float* __restrict__ ws, int obj_blocks)
{
    const int bx = blockIdx.x;
    const int tid = threadIdx.x;

    if (bx < obj_blocks) {
        // ---- softplus(obj) full reduction, float4-vectorized ----
        // float4 counts: scale0 = 25600, scale1 = 6400, scale2 = 1600 (total 33600)
        __shared__ float ssum[3];
        if (tid < 3) ssum[tid] = 0.0f;
        __syncthreads();
        const int gi = bx * 256 + tid;  // global float4 index
        if (gi < 33600) {
            const float4* p; int scale, li;
            if (gi < 25600)      { p = (const float4*)obj0; li = gi;         scale = 0; }
            else if (gi < 32000) { p = (const float4*)obj1; li = gi - 25600; scale = 1; }
            else                 { p = (const float4*)obj2; li = gi - 32000; scale = 2; }
            const float4 v = p[li];
            const float s = softplusf(v.x) + softplusf(v.y) + softplusf(v.z) + softplusf(v.w);
            atomicAdd(&ssum[scale], s);
        }
        __syncthreads();
        if (tid < 3 && ssum[tid] != 0.0f) atomicAdd(&ws[tid * 8 + 0], ssum[tid]);
    } else {
        // ---- per-scale assignment + positive-cell losses ----
        const int scale = bx - obj_blocks;
        const float* cls; const float* reg; const float* obj; int H, W;
        if (scale == 0)      { cls = cls0; reg = reg0; obj = obj0; H = 80; W = 80; }
        else if (scale == 1) { cls = cls1; reg = reg1; obj = obj1; H = 40; W = 40; }
        else                 { cls = cls2; reg = reg2; obj = obj2; H = 20; W = 20; }
        const int HW = H * W;

        __shared__ int   s_cell[NB];
        __shared__ int   s_lab[NB];
        __shared__ float s_acc[4];  // ce, sl1, npos, pos-obj
        if (tid < 4) s_acc[tid] = 0.0f;

        for (int j = tid; j < NB; j += 256) {
            const float cx = boxes[j * 4 + 0];
            const float cy = boxes[j * 4 + 1];
            int gx = (int)(cx * (float)W); gx = max(0, min(W - 1, gx));
            int gy = (int)(cy * (float)H); gy = max(0, min(H - 1, gy));
            s_cell[j] = gy * W + gx;
            s_lab[j]  = labels[j];
        }
        __syncthreads();

        for (int j = tid; j < NB; j += 256) {
            const int b    = j >> 6;
            const int n    = j & 63;
            const int cell = s_cell[j];
            const int base = b << 6;
            // scatter .set with duplicates: last write wins -> box j owns its
            // cell iff no later box (same batch) maps to the same cell
            bool winner = true;
            for (int m = n + 1; m < NBOX; ++m)
                if (s_cell[base + m] == cell) { winner = false; break; }
            if (!winner) continue;
            // argmax of multi-hot one-target row, ties -> lowest index:
            // min label among all boxes sharing this cell
            int minlab = 1 << 30;
            for (int m = 0; m < NBOX; ++m)
                if (s_cell[base + m] == cell) minlab = min(minlab, s_lab[base + m]);

            // cross-entropy: logsumexp over 30 strided logits
            const float* cb = cls + (size_t)b * NCLS * HW + cell;
            float v[NCLS];
            float mx = -INFINITY;
            #pragma unroll
            for (int c = 0; c < NCLS; ++c) { v[c] = cb[(size_t)c * HW]; mx = fmaxf(mx, v[c]); }
            float se = 0.0f;
            #pragma unroll
            for (int c = 0; c < NCLS; ++c) se += expf(v[c] - mx);
            const float ce = mx + logf(se) - v[minlab];

            // smooth-L1 (beta=1) vs winner's own box (last-write target), mean/4, clamp 10
            const float* rb = reg + (size_t)b * 4 * HW + cell;
            float sl = 0.0f;
            #pragma unroll
            for (int k = 0; k < 4; ++k) {
                const float d = fabsf(rb[(size_t)k * HW] - boxes[j * 4 + k]);
                sl += (d < 1.0f) ? 0.5f * d * d : (d - 0.5f);
            }
            sl *= 0.25f;
            sl = fminf(sl, 10.0f);

            const float po = obj[(size_t)b * HW + cell];

            atomicAdd(&s_acc[0], ce);
            atomicAdd(&s_acc[1], sl);
            atomicAdd(&s_acc[2], 1.0f);
            atomicAdd(&s_acc[3], po);
        }
        __syncthreads();
        if (tid < 4) atomicAdd(&ws[scale * 8 + 1 + tid], s_acc[tid]);
    }
}

__global__ void detloss_final(const float* __restrict__ ws, float* __restrict__ out)
{
    if (blockIdx.x == 0 && threadIdx.x == 0) {
        const float Ms[3] = { 16.0f * 6400.0f, 16.0f * 1600.0f, 16.0f * 400.0f };
        float clsl = 0.0f, regl = 0.0f, objl = 0.0f;
        for (int s = 0; s < 3; ++s) {
            const float npos = fmaxf(ws[s * 8 + 3], 1.0f);
            clsl += ws[s * 8 + 1] / npos;                    // CLS_W = 1
            regl += 5.0f * ws[s * 8 + 2] / npos;             // REG_W = 5
            objl += (ws[s * 8 + 0] - ws[s * 8 + 4]) / Ms[s]; // OBJ_W = 1
        }
        clsl /= 3.0f; regl /= 3.0f; objl /= 3.0f;
        out[0] = clsl + regl + objl;
        out[1] = clsl;
        out[2] = regl;
        out[3] = objl;
    }
}

extern "C" void kernel_launch(void* const* d_in, const int* in_sizes, int n_in,
                              void* d_out, int out_size, void* d_ws, size_t ws_size,
                              hipStream_t stream) {
    // setup_inputs dict order:
    // 0:cls_p0 1:reg_p0 2:obj_p0 3:cls_p1 4:reg_p1 5:obj_p1 6:cls_p2 7:reg_p2 8:obj_p2 9:boxes 10:labels
    const float* cls0  = (const float*)d_in[0];
    const float* reg0  = (const float*)d_in[1];
    const float* obj0  = (const float*)d_in[2];
    const float* cls1  = (const float*)d_in[3];
    const float* reg1  = (const float*)d_in[4];
    const float* obj1  = (const float*)d_in[5];
    const float* cls2  = (const float*)d_in[6];
    const float* reg2  = (const float*)d_in[7];
    const float* obj2  = (const float*)d_in[8];
    const float* boxes = (const float*)d_in[9];
    const int*   labels = (const int*)d_in[10];
    float* ws  = (float*)d_ws;
    float* out = (float*)d_out;

    hipMemsetAsync(ws, 0, 32 * sizeof(float), stream);

    const int obj_blocks = (33600 + 255) / 256;  // 132 float4-blocks
    detloss_main<<<dim3(obj_blocks + 3), 256, 0, stream>>>(
        cls0, reg0, obj0, cls1, reg1, obj1, cls2, reg2, obj2,
        boxes, labels, ws, obj_blocks);
    detloss_final<<<1, 64, 0, stream>>>(ws, out);
}

// Round 2
// 99.102 us; speedup vs baseline: 1.7744x; 1.7744x over previous
//
#include <hip/hip_runtime.h>
#include <math.h>

#define NCLS 30
#define OBJ_BLOCKS 132   // ceil(33600 float4 / 256)
#define POS_BLOCKS 12    // 12 blocks x 4 waves = 48 (scale,batch) tasks
#define NTASK 48

// ws layout (floats, no atomics, every slot below written unconditionally):
//   obj block i (0..131): ws[i*4 + s]       = partial softplus sum for scale s
//   pos task  t (0..47) : ws[(132+t)*4 + k] = {ce_sum, sl1_sum, npos, pos_obj_sum}

__device__ __forceinline__ float softplusf(float x) {
    return (x > 20.0f) ? x : log1pf(__expf(x));
}

__global__ __launch_bounds__(256) void detloss_main(
    const float* __restrict__ cls0, const float* __restrict__ reg0, const float* __restrict__ obj0,
    const float* __restrict__ cls1, const float* __restrict__ reg1, const float* __restrict__ obj1,
    const float* __restrict__ cls2, const float* __restrict__ reg2, const float* __restrict__ obj2,
    const float* __restrict__ boxes, const int* __restrict__ labels,
    float* __restrict__ ws)
{
    const int bx = blockIdx.x;
    const int tid = threadIdx.x;
    const int wave = tid >> 6;
    const int lane = tid & 63;

    if (bx < OBJ_BLOCKS) {
        // ---- softplus(obj) reduction, float4-vectorized, tree-reduced ----
        float a0 = 0.0f, a1 = 0.0f, a2 = 0.0f;
        const int gi = bx * 256 + tid;  // global float4 index, 33600 total
        if (gi < 33600) {
            const float4* p; int li;
            if (gi < 25600)      { p = (const float4*)obj0; li = gi; }
            else if (gi < 32000) { p = (const float4*)obj1; li = gi - 25600; }
            else                 { p = (const float4*)obj2; li = gi - 32000; }
            const float4 v = p[li];
            const float s = softplusf(v.x) + softplusf(v.y) + softplusf(v.z) + softplusf(v.w);
            if (gi < 25600) a0 = s; else if (gi < 32000) a1 = s; else a2 = s;
        }
        #pragma unroll
        for (int m = 32; m > 0; m >>= 1) {
            a0 += __shfl_xor(a0, m);
            a1 += __shfl_xor(a1, m);
            a2 += __shfl_xor(a2, m);
        }
        __shared__ float red[4][3];
        if (lane == 0) { red[wave][0] = a0; red[wave][1] = a1; red[wave][2] = a2; }
        __syncthreads();
        if (tid < 3) {
            ws[bx * 4 + tid] = red[0][tid] + red[1][tid] + red[2][tid] + red[3][tid];
        }
    } else {
        // ---- positive-cell losses: one wave per (scale,batch), one lane per box ----
        const int task  = (bx - OBJ_BLOCKS) * 4 + wave;  // 0..47
        const int scale = task >> 4;
        const int batch = task & 15;
        const float* cls; const float* reg; const float* obj; int H, W;
        if (scale == 0)      { cls = cls0; reg = reg0; obj = obj0; H = 80; W = 80; }
        else if (scale == 1) { cls = cls1; reg = reg1; obj = obj1; H = 40; W = 40; }
        else                 { cls = cls2; reg = reg2; obj = obj2; H = 20; W = 20; }
        const int HW = H * W;

        const int j = batch * 64 + lane;                 // global box id
        const float4 bv = ((const float4*)boxes)[j];     // cx,cy,w,h
        const int lab = labels[j];
        int gx = (int)(bv.x * (float)W); gx = max(0, min(W - 1, gx));
        int gy = (int)(bv.y * (float)H); gy = max(0, min(H - 1, gy));
        const int cell = gy * W + gx;

        // winner = no later box (same batch) maps to same cell (scatter last-write-wins)
        // minlab = min label among boxes sharing the cell (argmax ties -> lowest idx)
        bool winner = true;
        int minlab = 1 << 30;
        for (int m = 0; m < 64; ++m) {
            const int oc = __shfl(cell, m);
            const int ol = __shfl(lab, m);
            if (oc == cell) {
                if (m > lane) winner = false;
                minlab = min(minlab, ol);
            }
        }

        float ce = 0.0f, sl = 0.0f, npos = 0.0f, po = 0.0f;
        if (winner) {
            // cross-entropy via 30 strided logits kept in registers (static unroll)
            const float* cb = cls + (size_t)batch * NCLS * HW + cell;
            float v[NCLS];
            float mx = -INFINITY;
            #pragma unroll
            for (int c = 0; c < NCLS; ++c) { v[c] = cb[(size_t)c * HW]; mx = fmaxf(mx, v[c]); }
            float se = 0.0f, tgt = 0.0f;
            #pragma unroll
            for (int c = 0; c < NCLS; ++c) {
                se += __expf(v[c] - mx);
                if (c == minlab) tgt = v[c];   // cndmask, minlab known pre-gather
            }
            ce = mx + __logf(se) - tgt;

            // smooth-L1 (beta=1) vs own box (last-write target), mean/4, clamp 10
            const float* rb = reg + (size_t)batch * 4 * HW + cell;
            const float t[4] = { bv.x, bv.y, bv.z, bv.w };
            #pragma unroll
            for (int k = 0; k < 4; ++k) {
                const float d = fabsf(rb[(size_t)k * HW] - t[k]);
                sl += (d < 1.0f) ? 0.5f * d * d : (d - 0.5f);
            }
            sl = fminf(sl * 0.25f, 10.0f);

            po = obj[(size_t)batch * HW + cell];
            npos = 1.0f;
        }
        #pragma unroll
        for (int m = 32; m > 0; m >>= 1) {
            ce   += __shfl_xor(ce, m);
            sl   += __shfl_xor(sl, m);
            npos += __shfl_xor(npos, m);
            po   += __shfl_xor(po, m);
        }
        if (lane == 0) {
            float* o = ws + (size_t)(OBJ_BLOCKS + task) * 4;
            o[0] = ce; o[1] = sl; o[2] = npos; o[3] = po;
        }
    }
}

__global__ __launch_bounds__(256) void detloss_final(
    const float* __restrict__ ws, float* __restrict__ out)
{
    const int tid = threadIdx.x;
    const int wave = tid >> 6;
    const int lane = tid & 63;

    // per-thread strided partials: 15 accumulators = 3 scales x {softplus, ce, sl, npos, po}
    float acc[15];
    #pragma unroll
    for (int k = 0; k < 15; ++k) acc[k] = 0.0f;

    for (int i = tid; i < OBJ_BLOCKS; i += 256) {
        acc[0] += ws[i * 4 + 0];
        acc[1] += ws[i * 4 + 1];
        acc[2] += ws[i * 4 + 2];
    }
    for (int t = tid; t < NTASK; t += 256) {
        const int s = t >> 4;
        const float* o = ws + (size_t)(OBJ_BLOCKS + t) * 4;
        acc[3 + s * 4 + 0] += o[0];
        acc[3 + s * 4 + 1] += o[1];
        acc[3 + s * 4 + 2] += o[2];
        acc[3 + s * 4 + 3] += o[3];
    }
    #pragma unroll
    for (int m = 32; m > 0; m >>= 1)
        #pragma unroll
        for (int k = 0; k < 15; ++k) acc[k] += __shfl_xor(acc[k], m);

    __shared__ float red[4][15];
    if (lane == 0)
        #pragma unroll
        for (int k = 0; k < 15; ++k) red[wave][k] = acc[k];
    __syncthreads();

    if (tid == 0) {
        float f[15];
        #pragma unroll
        for (int k = 0; k < 15; ++k) f[k] = red[0][k] + red[1][k] + red[2][k] + red[3][k];
        const float Ms[3] = { 16.0f * 6400.0f, 16.0f * 1600.0f, 16.0f * 400.0f };
        float clsl = 0.0f, regl = 0.0f, objl = 0.0f;
        for (int s = 0; s < 3; ++s) {
            const float npos = fmaxf(f[3 + s * 4 + 2], 1.0f);
            clsl += f[3 + s * 4 + 0] / npos;                 // CLS_W = 1
            regl += 5.0f * f[3 + s * 4 + 1] / npos;          // REG_W = 5
            objl += (f[s] - f[3 + s * 4 + 3]) / Ms[s];       // OBJ_W = 1
        }
        clsl /= 3.0f; regl /= 3.0f; objl /= 3.0f;
        out[0] = clsl + regl + objl;
        out[1] = clsl;
        out[2] = regl;
        out[3] = objl;
    }
}

extern "C" void kernel_launch(void* const* d_in, const int* in_sizes, int n_in,
                              void* d_out, int out_size, void* d_ws, size_t ws_size,
                              hipStream_t stream) {
    const float* cls0   = (const float*)d_in[0];
    const float* reg0   = (const float*)d_in[1];
    const float* obj0   = (const float*)d_in[2];
    const float* cls1   = (const float*)d_in[3];
    const float* reg1   = (const float*)d_in[4];
    const float* obj1   = (const float*)d_in[5];
    const float* cls2   = (const float*)d_in[6];
    const float* reg2   = (const float*)d_in[7];
    const float* obj2   = (const float*)d_in[8];
    const float* boxes  = (const float*)d_in[9];
    const int*   labels = (const int*)d_in[10];
    float* ws  = (float*)d_ws;
    float* out = (float*)d_out;

    detloss_main<<<dim3(OBJ_BLOCKS + POS_BLOCKS), 256, 0, stream>>>(
        cls0, reg0, obj0, cls1, reg1, obj1, cls2, reg2, obj2,
        boxes, labels, ws);
    detloss_final<<<1, 256, 0, stream>>>(ws, out);
}

// Round 3
// 96.540 us; speedup vs baseline: 1.8216x; 1.0265x over previous
//
#include <hip/hip_runtime.h>
#include <math.h>

#define NCLS 30
#define OBJ_BLOCKS 132        // ceil(33600 float4 / 256)
#define POS_BLOCKS 12         // 12 blocks x 4 waves = 48 (scale,batch) tasks
#define TOTAL_BLOCKS (OBJ_BLOCKS + POS_BLOCKS)

// ws layout:
//   float ws[s*5 + 0] = sum softplus(obj) over all cells   (scale s)
//   float ws[s*5 + 1] = sum ce over positive cells
//   float ws[s*5 + 2] = sum smoothL1 over positive cells
//   float ws[s*5 + 3] = npos
//   float ws[s*5 + 4] = sum obj logits over positive cells
//   ((unsigned*)ws)[15] = done-block counter
// All zeroed by a 64 B memset node before the kernel.

__device__ __forceinline__ float softplusf(float x) {
    return (x > 20.0f) ? x : log1pf(__expf(x));
}

__global__ __launch_bounds__(256) void detloss_fused(
    const float* __restrict__ cls0, const float* __restrict__ reg0, const float* __restrict__ obj0,
    const float* __restrict__ cls1, const float* __restrict__ reg1, const float* __restrict__ obj1,
    const float* __restrict__ cls2, const float* __restrict__ reg2, const float* __restrict__ obj2,
    const float* __restrict__ boxes, const int* __restrict__ labels,
    float* __restrict__ ws, float* __restrict__ out)
{
    const int bx = blockIdx.x;
    const int tid = threadIdx.x;
    const int wave = tid >> 6;
    const int lane = tid & 63;

    if (bx < OBJ_BLOCKS) {
        // ---- softplus(obj) reduction, float4-vectorized, shfl tree-reduced ----
        float a0 = 0.0f, a1 = 0.0f, a2 = 0.0f;
        const int gi = bx * 256 + tid;  // global float4 index, 33600 total
        if (gi < 33600) {
            const float4* p; int li;
            if (gi < 25600)      { p = (const float4*)obj0; li = gi; }
            else if (gi < 32000) { p = (const float4*)obj1; li = gi - 25600; }
            else                 { p = (const float4*)obj2; li = gi - 32000; }
            const float4 v = p[li];
            const float s = softplusf(v.x) + softplusf(v.y) + softplusf(v.z) + softplusf(v.w);
            if (gi < 25600) a0 = s; else if (gi < 32000) a1 = s; else a2 = s;
        }
        #pragma unroll
        for (int m = 32; m > 0; m >>= 1) {
            a0 += __shfl_xor(a0, m);
            a1 += __shfl_xor(a1, m);
            a2 += __shfl_xor(a2, m);
        }
        __shared__ float red[4][3];
        if (lane == 0) { red[wave][0] = a0; red[wave][1] = a1; red[wave][2] = a2; }
        __syncthreads();
        if (tid < 3) {
            const float v = red[0][tid] + red[1][tid] + red[2][tid] + red[3][tid];
            atomicAdd(&ws[tid * 5 + 0], v);
        }
    } else {
        // ---- positive-cell losses: one wave per (scale,batch), one lane per box ----
        const int task  = (bx - OBJ_BLOCKS) * 4 + wave;  // 0..47
        const int scale = task >> 4;
        const int batch = task & 15;
        const float* cls; const float* reg; const float* obj; int H, W;
        if (scale == 0)      { cls = cls0; reg = reg0; obj = obj0; H = 80; W = 80; }
        else if (scale == 1) { cls = cls1; reg = reg1; obj = obj1; H = 40; W = 40; }
        else                 { cls = cls2; reg = reg2; obj = obj2; H = 20; W = 20; }
        const int HW = H * W;

        const int j = batch * 64 + lane;                 // global box id
        const float4 bv = ((const float4*)boxes)[j];     // cx,cy,w,h
        const int lab = labels[j];
        int gx = (int)(bv.x * (float)W); gx = max(0, min(W - 1, gx));
        int gy = (int)(bv.y * (float)H); gy = max(0, min(H - 1, gy));
        const int cell = gy * W + gx;

        // winner = no later box (same batch) maps to same cell (scatter last-write-wins)
        // minlab = min label among boxes sharing the cell (argmax ties -> lowest idx)
        bool winner = true;
        int minlab = 1 << 30;
        for (int m = 0; m < 64; ++m) {
            const int oc = __shfl(cell, m);
            const int ol = __shfl(lab, m);
            if (oc == cell) {
                if (m > lane) winner = false;
                minlab = min(minlab, ol);
            }
        }

        float ce = 0.0f, sl = 0.0f, npos = 0.0f, po = 0.0f;
        if (winner) {
            // cross-entropy via 30 strided logits kept in registers (static unroll)
            const float* cb = cls + (size_t)batch * NCLS * HW + cell;
            float v[NCLS];
            float mx = -INFINITY;
            #pragma unroll
            for (int c = 0; c < NCLS; ++c) { v[c] = cb[(size_t)c * HW]; mx = fmaxf(mx, v[c]); }
            float se = 0.0f, tgt = 0.0f;
            #pragma unroll
            for (int c = 0; c < NCLS; ++c) {
                se += __expf(v[c] - mx);
                if (c == minlab) tgt = v[c];   // cndmask, minlab known pre-gather
            }
            ce = mx + __logf(se) - tgt;

            // smooth-L1 (beta=1) vs own box (last-write target), mean/4, clamp 10
            const float* rb = reg + (size_t)batch * 4 * HW + cell;
            const float t[4] = { bv.x, bv.y, bv.z, bv.w };
            #pragma unroll
            for (int k = 0; k < 4; ++k) {
                const float d = fabsf(rb[(size_t)k * HW] - t[k]);
                sl += (d < 1.0f) ? 0.5f * d * d : (d - 0.5f);
            }
            sl = fminf(sl * 0.25f, 10.0f);

            po = obj[(size_t)batch * HW + cell];
            npos = 1.0f;
        }
        #pragma unroll
        for (int m = 32; m > 0; m >>= 1) {
            ce   += __shfl_xor(ce, m);
            sl   += __shfl_xor(sl, m);
            npos += __shfl_xor(npos, m);
            po   += __shfl_xor(po, m);
        }
        if (lane == 0) {
            atomicAdd(&ws[scale * 5 + 1], ce);
            atomicAdd(&ws[scale * 5 + 2], sl);
            atomicAdd(&ws[scale * 5 + 3], npos);
            atomicAdd(&ws[scale * 5 + 4], po);
        }
        __syncthreads();  // pos blocks: all waves' atomics issued before counter bump
    }

    // ---- last-block-done finalize (single kernel, no second launch) ----
    if (bx < OBJ_BLOCKS) __syncthreads();   // obj blocks: atomics by tid<3 done
    if (tid == 0) {
        __threadfence();  // release: fp accumulator atomics visible before counter
        unsigned* ctr = (unsigned*)ws + 15;
        const unsigned old = atomicAdd(ctr, 1u);
        if (old == TOTAL_BLOCKS - 1) {
            __threadfence();  // acquire
            float f[15];
            #pragma unroll
            for (int k = 0; k < 15; ++k)
                f[k] = __hip_atomic_load(&ws[k], __ATOMIC_RELAXED, __HIP_MEMORY_SCOPE_AGENT);
            const float Ms[3] = { 16.0f * 6400.0f, 16.0f * 1600.0f, 16.0f * 400.0f };
            float clsl = 0.0f, regl = 0.0f, objl = 0.0f;
            #pragma unroll
            for (int s = 0; s < 3; ++s) {
                const float npos = fmaxf(f[s * 5 + 3], 1.0f);
                clsl += f[s * 5 + 1] / npos;                 // CLS_W = 1
                regl += 5.0f * f[s * 5 + 2] / npos;          // REG_W = 5
                objl += (f[s * 5 + 0] - f[s * 5 + 4]) / Ms[s]; // OBJ_W = 1
            }
            clsl /= 3.0f; regl /= 3.0f; objl /= 3.0f;
            out[0] = clsl + regl + objl;
            out[1] = clsl;
            out[2] = regl;
            out[3] = objl;
        }
    }
}

extern "C" void kernel_launch(void* const* d_in, const int* in_sizes, int n_in,
                              void* d_out, int out_size, void* d_ws, size_t ws_size,
                              hipStream_t stream) {
    const float* cls0   = (const float*)d_in[0];
    const float* reg0   = (const float*)d_in[1];
    const float* obj0   = (const float*)d_in[2];
    const float* cls1   = (const float*)d_in[3];
    const float* reg1   = (const float*)d_in[4];
    const float* obj1   = (const float*)d_in[5];
    const float* cls2   = (const float*)d_in[6];
    const float* reg2   = (const float*)d_in[7];
    const float* obj2   = (const float*)d_in[8];
    const float* boxes  = (const float*)d_in[9];
    const int*   labels = (const int*)d_in[10];
    float* ws  = (float*)d_ws;
    float* out = (float*)d_out;

    hipMemsetAsync(ws, 0, 64, stream);  // zero 15 fp accumulators + counter

    detloss_fused<<<dim3(TOTAL_BLOCKS), 256, 0, stream>>>(
        cls0, reg0, obj0, cls1, reg1, obj1, cls2, reg2, obj2,
        boxes, labels, ws, out);
}